// Round 11
// baseline (118.903 us; speedup 1.0000x reference)
//
#include <hip/hip_runtime.h>
#include <math.h>

#define B_SZ 1024
#define E_SZ 512
#define C_SZ 16384
#define MRG 0.1f
#define ALPHA 32.0f
#define A2LOG2E 46.16624090918536f   /* ALPHA * log2(e) */
#define K_HY 1.0f
#define LAM 0.1f

#define BM 128
#define BN 256
#define BK 32          /* bf16 elements per K-tile */
#define NT (E_SZ / BK) /* 16 K-tiles */

typedef __bf16 bf16;
typedef bf16 bf16x8 __attribute__((ext_vector_type(8)));
typedef float f32x4 __attribute__((ext_vector_type(4)));

__device__ __forceinline__ void async16(const void* g, void* l) {
    __builtin_amdgcn_global_load_lds(
        (const __attribute__((address_space(1))) void*)g,
        (__attribute__((address_space(3))) void*)l,
        16, 0, 0);
}

// ---------------- fused prep: proxy_norm | convert_inputs | class_scalars | zero-accum
__global__ __launch_bounds__(256) void prep_fused(
    const float* __restrict__ proxies, bf16* __restrict__ Pbf,
    const float* __restrict__ inputs, bf16* __restrict__ Abf,
    const float* __restrict__ effNum, const float* __restrict__ lSim,
    float* __restrict__ oSim, float* __restrict__ iEff,
    float* __restrict__ zeroBase) {
    const int blk = blockIdx.x;
    const int tid = threadIdx.x;
    if (blk < 4096) {
        int row = blk * 4 + (tid >> 6);
        int lane = tid & 63;
        const float* pr = proxies + (size_t)row * E_SZ + lane * 8;
        float4 v0 = *(const float4*)pr;
        float4 v1 = *(const float4*)(pr + 4);
        float ss = v0.x * v0.x + v0.y * v0.y + v0.z * v0.z + v0.w * v0.w +
                   v1.x * v1.x + v1.y * v1.y + v1.z * v1.z + v1.w * v1.w;
#pragma unroll
        for (int m = 1; m < 64; m <<= 1) ss += __shfl_xor(ss, m);
        float inv = 1.0f / sqrtf(ss + 1e-12f);
        bf16x8 o;
        o[0] = (bf16)(v0.x * inv); o[1] = (bf16)(v0.y * inv);
        o[2] = (bf16)(v0.z * inv); o[3] = (bf16)(v0.w * inv);
        o[4] = (bf16)(v1.x * inv); o[5] = (bf16)(v1.y * inv);
        o[6] = (bf16)(v1.z * inv); o[7] = (bf16)(v1.w * inv);
        *(bf16x8*)(Pbf + (size_t)row * E_SZ + lane * 8) = o;
    } else if (blk < 4352) {
        int i = ((blk - 4096) * 256 + tid) * 8;
        float4 v0 = *(const float4*)(inputs + i);
        float4 v1 = *(const float4*)(inputs + i + 4);
        bf16x8 o;
        o[0] = (bf16)v0.x; o[1] = (bf16)v0.y; o[2] = (bf16)v0.z; o[3] = (bf16)v0.w;
        o[4] = (bf16)v1.x; o[5] = (bf16)v1.y; o[6] = (bf16)v1.z; o[7] = (bf16)v1.w;
        *(bf16x8*)(Abf + i) = o;
    } else if (blk < 4416) {
        int c = (blk - 4352) * 256 + tid;     // exactly covers [0, C_SZ)
        float en = effNum[c], ls = lSim[c];
        float wb = 1.0f / (1.0f + log1pf(en));
        float eta = (1.0f + K_HY * (1.0f - ls)) * wb + LAM;
        oSim[c] = ls - eta;
        iEff[c] = 1.0f / fmaxf(1.0f, en);
    } else {
        // zero 4*C_SZ + 8 floats (posExp,negExp,negVals,cCnt,acc4,counter,pad)
        int i = (blk - 4416) * 256 + tid;
        if (i < 16386) {
            float4 z = {0.f, 0.f, 0.f, 0.f};
            *(float4*)(zeroBase + (size_t)i * 4) = z;
        }
    }
}

// ---------------- fused GEMM (bf16 MFMA) + epilogue ----------------
// r10 skeleton + DEPTH-2 PREFETCH (the single change this round):
// 3 LDS buffers; at tile t stage tile t+2; steady-state in-flight =
// {S(t+1), S(t+2)} = 6 loads, so vmcnt(6) retires exactly tile-t's 3
// (FIFO). Stage->use distance doubles to ~2 tile-iterations, covering
// L2/L3-warm global_load_lds latency that the 1-deep r4/r10 loops paid
// serially per tile (both measured ~40 us despite different occupancy —
// lock-stepped twin blocks can't hide each other's stalls).
// Tail: vmcnt(3) at t=NT-2, vmcnt(0) at t=NT-1.
// WAR: buf[(t+2)%3] was last read at tile t-1; those ds_reads drain
// (compiler lgkmcnt before MFMA) before BARRIER_A(t).
// LDS = 72 KB buffers + ~2.5 KB scratch => still 2 blocks/CU.
__global__ __launch_bounds__(512, 4) void gemm_epilogue(
    const bf16* __restrict__ Abf,   // [B][E]
    const bf16* __restrict__ Pbf,   // [C][E] normalized
    const int* __restrict__ targets,
    const float* __restrict__ oSimA,
    const float* __restrict__ iEffA,
    float* __restrict__ posExp,
    float* __restrict__ negExp,
    float* __restrict__ negVals,
    int* __restrict__ cCnt) {
    __shared__ __align__(16) bf16 Alds[3][BM * BK];   // 3 x 8 KB
    __shared__ __align__(16) bf16 Blds[3][BN * BK];   // 3 x 16 KB
    __shared__ int tgtLds[BM];
    __shared__ float scratch[2 * BN];

    const int tid = threadIdx.x;
    const int wave = tid >> 6, lane = tid & 63;
    const int quad = lane >> 4, l16 = lane & 15;
    const int wm = wave >> 2, wn = wave & 3;          // 2M x 4N wave grid
    const int bn0 = blockIdx.x * BN, bm0 = blockIdx.y * BM;

    if (tid < BM) tgtLds[tid] = targets[bm0 + tid];

    f32x4 zero = {0.f, 0.f, 0.f, 0.f};
    f32x4 acc[4][4];
#pragma unroll
    for (int i = 0; i < 4; ++i)
#pragma unroll
        for (int j = 0; j < 4; ++j) acc[i][j] = zero;

    // staging map: thread -> (row tid>>2, 16B k-slot tid&3)
    const bf16* gAs = Abf + (size_t)(bm0 + (tid >> 2)) * E_SZ + (tid & 3) * 8;
    const bf16* gBs = Pbf + (size_t)(bn0 + (tid >> 2)) * E_SZ + (tid & 3) * 8;

    // fragment read bases (elements) within a [rows][32] plane
    const int aBase = (wm * 64 + l16) * BK + quad * 8;
    const int bBase = (wn * 64 + l16) * BK + quad * 8;

    __syncthreads();   // full drain: vmcnt==0 for every wave entering the loop

    // prologue: stage K-tiles 0 and 1 into buffers 0 and 1 (6 loads/thread)
#pragma unroll
    for (int p = 0; p < 2; ++p) {
        const int kOff = p * BK;
        async16(gAs + kOff, &Alds[p][tid * 8]);
        async16(gBs + kOff, &Blds[p][tid * 8]);
        async16(gBs + (size_t)128 * E_SZ + kOff, &Blds[p][4096 + tid * 8]);
    }

#pragma unroll
    for (int t = 0; t < NT; ++t) {
        const int cur = t % 3;
        // BARRIER_A: everyone finished reading buf[(t-1)%3] == buf[(t+2)%3]
        __builtin_amdgcn_s_barrier();
        __builtin_amdgcn_sched_barrier(0);
        if (t < NT - 2) {
            const int nxt2 = (t + 2) % 3;
            const int kOff = (t + 2) * BK;
            async16(gAs + kOff, &Alds[nxt2][tid * 8]);
            async16(gBs + kOff, &Blds[nxt2][tid * 8]);
            async16(gBs + (size_t)128 * E_SZ + kOff, &Blds[nxt2][4096 + tid * 8]);
            // in flight: S(t),S(t+1),S(t+2)=9 -> retire S(t), keep 6
            asm volatile("s_waitcnt vmcnt(6)" ::: "memory");
        } else if (t == NT - 2) {
            // in flight: S(t),S(t+1)=6 -> retire S(t), keep S(t+1)
            asm volatile("s_waitcnt vmcnt(3)" ::: "memory");
        } else {
            asm volatile("s_waitcnt vmcnt(0)" ::: "memory");
        }
        // BARRIER_B: all waves' tile-t loads have landed in buf[cur]
        __builtin_amdgcn_s_barrier();
        __builtin_amdgcn_sched_barrier(0);

        bf16x8 af[4], bfr[4];
#pragma unroll
        for (int mi = 0; mi < 4; ++mi)
            af[mi] = *(const bf16x8*)&Alds[cur][aBase + mi * 16 * BK];
#pragma unroll
        for (int ni = 0; ni < 4; ++ni)
            bfr[ni] = *(const bf16x8*)&Blds[cur][bBase + ni * 16 * BK];
#pragma unroll
        for (int mi = 0; mi < 4; ++mi)
#pragma unroll
            for (int ni = 0; ni < 4; ++ni)
                acc[mi][ni] = __builtin_amdgcn_mfma_f32_16x16x32_bf16(
                    af[mi], bfr[ni], acc[mi][ni], 0, 0, 0);
    }
    __builtin_amdgcn_sched_barrier(0);  // keep epilogue loads out of the K-loop

    // -------- epilogue: per-class (column) reductions --------
    int colG[4];
    float oS[4], iE[4];
#pragma unroll
    for (int ni = 0; ni < 4; ++ni) {
        colG[ni] = bn0 + wn * 64 + ni * 16 + l16;
        oS[ni] = oSimA[colG[ni]];
        iE[ni] = iEffA[colG[ni]];
    }
    float negE[4] = {0.f, 0.f, 0.f, 0.f};
    float negV[4] = {0.f, 0.f, 0.f, 0.f};
#pragma unroll
    for (int mi = 0; mi < 4; ++mi) {
#pragma unroll
        for (int r = 0; r < 4; ++r) {
            int rowL = wm * 64 + mi * 16 + quad * 4 + r;
            int tgt = tgtLds[rowL];
#pragma unroll
            for (int ni = 0; ni < 4; ++ni) {
                float cosv = acc[mi][ni][r];
                if (tgt == colG[ni]) {
                    // positive position (exactly one (bx,by) block per row)
                    atomicAdd(&posExp[colG[ni]],
                              __builtin_amdgcn_exp2f(A2LOG2E * (MRG - cosv)));
                    atomicAdd(&cCnt[colG[ni]], 1);
                } else {
                    float nv = (cosv < oS[ni]) ? iE[ni] : 1.0f;
                    negE[ni] += __builtin_amdgcn_exp2f(A2LOG2E * (cosv + MRG) * nv);
                    negV[ni] += nv;
                }
            }
        }
    }
    // quad-level register reduce: quad==0 lane holds the 64-row partial
#pragma unroll
    for (int ni = 0; ni < 4; ++ni) {
        negE[ni] += __shfl_xor(negE[ni], 16); negE[ni] += __shfl_xor(negE[ni], 32);
        negV[ni] += __shfl_xor(negV[ni], 16); negV[ni] += __shfl_xor(negV[ni], 32);
    }
    // combine the two wm-waves per column range in LDS, then one coalesced
    // global atomic per column.
    float* nEsh = scratch;          // 256 floats
    float* nVsh = scratch + BN;     // 256 floats
    scratch[tid & 511] = 0.0f;      // 512 threads zero 512 floats
    __syncthreads();
    if (quad == 0) {
#pragma unroll
        for (int ni = 0; ni < 4; ++ni) {
            int cl = wn * 64 + ni * 16 + l16;
            atomicAdd(&nEsh[cl], negE[ni]);
            atomicAdd(&nVsh[cl], negV[ni]);
        }
    }
    __syncthreads();
    if (tid < BN) {
        atomicAdd(&negExp[bn0 + tid], nEsh[tid]);
        atomicAdd(&negVals[bn0 + tid], nVsh[tid]);
    }
}

// ---------------- finalize: 16 blocks, last-block-ticket completes ----------------
__global__ __launch_bounds__(256) void finalize(
    const float* __restrict__ posExp, const float* __restrict__ negExp,
    const float* __restrict__ negVals, const int* __restrict__ cCnt,
    float* __restrict__ acc4, int* __restrict__ counter,
    float* __restrict__ out) {
    const int tid = threadIdx.x;
    float pt = 0.f, nt = 0.f, pws = 0.f, nws = 0.f;
#pragma unroll
    for (int j = 0; j < 4; ++j) {
        int c = blockIdx.x * 1024 + j * 256 + tid;
        pt += log1pf(posExp[c]);
        nt += log1pf(negExp[c]);
        int cnt = cCnt[c];
        pws += (cnt > 0) ? 1.0f : 0.0f;
        int Nc = B_SZ - cnt;
        nws += (Nc > 0) ? negVals[c] / (float)Nc : 0.0f;
    }
#pragma unroll
    for (int m = 1; m < 64; m <<= 1) {
        pt += __shfl_xor(pt, m);
        nt += __shfl_xor(nt, m);
        pws += __shfl_xor(pws, m);
        nws += __shfl_xor(nws, m);
    }
    __shared__ float red[4][4];
    int wv = tid >> 6;
    if ((tid & 63) == 0) {
        red[wv][0] = pt; red[wv][1] = nt; red[wv][2] = pws; red[wv][3] = nws;
    }
    __syncthreads();
    if (tid < 4) {
        float s = red[0][tid] + red[1][tid] + red[2][tid] + red[3][tid];
        atomicAdd(&acc4[tid], s);
    }
    __syncthreads();
    __threadfence();
    if (tid == 0) {
        int ticket = atomicAdd(counter, 1);
        if (ticket == 15) {
            float a0 = atomicAdd(&acc4[0], 0.0f);
            float a1 = atomicAdd(&acc4[1], 0.0f);
            float a2 = atomicAdd(&acc4[2], 0.0f);
            float a3 = atomicAdd(&acc4[3], 0.0f);
            out[0] = a0 / a2 + a1 / a3;
        }
    }
}

extern "C" void kernel_launch(void* const* d_in, const int* in_sizes, int n_in,
                              void* d_out, int out_size, void* d_ws, size_t ws_size,
                              hipStream_t stream) {
    const float* inputs = (const float*)d_in[0];
    const int* targets = (const int*)d_in[1];
    const float* proxies = (const float*)d_in[2];
    const float* effNum = (const float*)d_in[3];
    const float* lSim = (const float*)d_in[4];
    float* out = (float*)d_out;

    // workspace layout
    bf16* Pbf = (bf16*)d_ws;                        // C*E bf16  (16 MB)
    bf16* Abf = Pbf + (size_t)C_SZ * E_SZ;          // B*E bf16  (1 MB)
    float* oSim = (float*)(Abf + (size_t)B_SZ * E_SZ);
    float* iEff = oSim + C_SZ;
    float* posExp = iEff + C_SZ;                    // zeroBase starts here
    float* negExp = posExp + C_SZ;
    float* negVals = negExp + C_SZ;
    int* cCnt = (int*)(negVals + C_SZ);
    float* acc4 = (float*)(cCnt + C_SZ);
    int* counter = (int*)(acc4 + 4);

    prep_fused<<<4481, 256, 0, stream>>>(proxies, Pbf, inputs, Abf,
                                         effNum, lSim, oSim, iEff, posExp);
    gemm_epilogue<<<dim3(C_SZ / BN, B_SZ / BM), 512, 0, stream>>>(
        Abf, Pbf, targets, oSim, iEff, posExp, negExp, negVals, cCnt);
    finalize<<<16, 256, 0, stream>>>(posExp, negExp, negVals, cCnt,
                                     acc4, counter, out);
}

// Round 20
// 117.092 us; speedup vs baseline: 1.0155x; 1.0155x over previous
//
#include <hip/hip_runtime.h>
#include <math.h>

#define B_SZ 1024
#define E_SZ 512
#define C_SZ 16384
#define MRG 0.1f
#define ALPHA 32.0f
#define A2LOG2E 46.16624090918536f   /* ALPHA * log2(e) */
#define K_HY 1.0f
#define LAM 0.1f

#define BM 128
#define BN 256
#define BK 32          /* bf16 elements per K-tile */
#define NT (E_SZ / BK) /* 16 K-tiles */

typedef __bf16 bf16;
typedef bf16 bf16x8 __attribute__((ext_vector_type(8)));
typedef float f32x4 __attribute__((ext_vector_type(4)));

__device__ __forceinline__ void async16(const void* g, void* l) {
    __builtin_amdgcn_global_load_lds(
        (const __attribute__((address_space(1))) void*)g,
        (__attribute__((address_space(3))) void*)l,
        16, 0, 0);
}

// ---------------- fused prep: proxy_norm | convert_inputs | class_scalars | zero-accum
__global__ __launch_bounds__(256) void prep_fused(
    const float* __restrict__ proxies, bf16* __restrict__ Pbf,
    const float* __restrict__ inputs, bf16* __restrict__ Abf,
    const float* __restrict__ effNum, const float* __restrict__ lSim,
    float* __restrict__ oSim, float* __restrict__ iEff,
    float* __restrict__ zeroBase) {
    const int blk = blockIdx.x;
    const int tid = threadIdx.x;
    if (blk < 4096) {
        int row = blk * 4 + (tid >> 6);
        int lane = tid & 63;
        const float* pr = proxies + (size_t)row * E_SZ + lane * 8;
        float4 v0 = *(const float4*)pr;
        float4 v1 = *(const float4*)(pr + 4);
        float ss = v0.x * v0.x + v0.y * v0.y + v0.z * v0.z + v0.w * v0.w +
                   v1.x * v1.x + v1.y * v1.y + v1.z * v1.z + v1.w * v1.w;
#pragma unroll
        for (int m = 1; m < 64; m <<= 1) ss += __shfl_xor(ss, m);
        float inv = 1.0f / sqrtf(ss + 1e-12f);
        bf16x8 o;
        o[0] = (bf16)(v0.x * inv); o[1] = (bf16)(v0.y * inv);
        o[2] = (bf16)(v0.z * inv); o[3] = (bf16)(v0.w * inv);
        o[4] = (bf16)(v1.x * inv); o[5] = (bf16)(v1.y * inv);
        o[6] = (bf16)(v1.z * inv); o[7] = (bf16)(v1.w * inv);
        *(bf16x8*)(Pbf + (size_t)row * E_SZ + lane * 8) = o;
    } else if (blk < 4352) {
        int i = ((blk - 4096) * 256 + tid) * 8;
        float4 v0 = *(const float4*)(inputs + i);
        float4 v1 = *(const float4*)(inputs + i + 4);
        bf16x8 o;
        o[0] = (bf16)v0.x; o[1] = (bf16)v0.y; o[2] = (bf16)v0.z; o[3] = (bf16)v0.w;
        o[4] = (bf16)v1.x; o[5] = (bf16)v1.y; o[6] = (bf16)v1.z; o[7] = (bf16)v1.w;
        *(bf16x8*)(Abf + i) = o;
    } else if (blk < 4416) {
        int c = (blk - 4352) * 256 + tid;     // exactly covers [0, C_SZ)
        float en = effNum[c], ls = lSim[c];
        float wb = 1.0f / (1.0f + log1pf(en));
        float eta = (1.0f + K_HY * (1.0f - ls)) * wb + LAM;
        oSim[c] = ls - eta;
        iEff[c] = 1.0f / fmaxf(1.0f, en);
    } else {
        // zero 4*C_SZ + 8 floats (posExp,negExp,negVals,cCnt,acc4,counter,pad)
        int i = (blk - 4416) * 256 + tid;
        if (i < 16386) {
            float4 z = {0.f, 0.f, 0.f, 0.f};
            *(float4*)(zeroBase + (size_t)i * 4) = z;
        }
    }
}

// ---------------- fused GEMM (bf16 MFMA) + epilogue ----------------
// r10 MEASURED FORM (117.2 us, passed): BM=128 x BN=256 x BK=32, 8 waves
// (2M x 4N), per-wave output 64x64. LDS 48KB + scratch, launch_bounds(512,4)
// => 2 blocks/CU. Double-buffered, counted vmcnt(3) 2-phase. [rows][32] LDS
// layout is bank-uniform for ds_read_b128 (b128 floor) -> linear staging,
// no swizzle. Grid 64x8 = 512 blocks.
__global__ __launch_bounds__(512, 4) void gemm_epilogue(
    const bf16* __restrict__ Abf,   // [B][E]
    const bf16* __restrict__ Pbf,   // [C][E] normalized
    const int* __restrict__ targets,
    const float* __restrict__ oSimA,
    const float* __restrict__ iEffA,
    float* __restrict__ posExp,
    float* __restrict__ negExp,
    float* __restrict__ negVals,
    int* __restrict__ cCnt) {
    __shared__ __align__(16) bf16 Alds[2][BM * BK];   // 2 x 8 KB
    __shared__ __align__(16) bf16 Blds[2][BN * BK];   // 2 x 16 KB
    __shared__ int tgtLds[BM];
    __shared__ float scratch[2 * BN];

    const int tid = threadIdx.x;
    const int wave = tid >> 6, lane = tid & 63;
    const int quad = lane >> 4, l16 = lane & 15;
    const int wm = wave >> 2, wn = wave & 3;          // 2M x 4N wave grid
    const int bn0 = blockIdx.x * BN, bm0 = blockIdx.y * BM;

    if (tid < BM) tgtLds[tid] = targets[bm0 + tid];

    f32x4 zero = {0.f, 0.f, 0.f, 0.f};
    f32x4 acc[4][4];
#pragma unroll
    for (int i = 0; i < 4; ++i)
#pragma unroll
        for (int j = 0; j < 4; ++j) acc[i][j] = zero;

    // staging map: thread -> (row tid>>2, 16B k-slot tid&3)
    const bf16* gAs = Abf + (size_t)(bm0 + (tid >> 2)) * E_SZ + (tid & 3) * 8;
    const bf16* gBs = Pbf + (size_t)(bn0 + (tid >> 2)) * E_SZ + (tid & 3) * 8;

    // fragment read bases (elements) within a [rows][32] plane
    const int aBase = (wm * 64 + l16) * BK + quad * 8;
    const int bBase = (wn * 64 + l16) * BK + quad * 8;

    __syncthreads();   // full drain: vmcnt==0 for every wave entering the loop

    // prologue: stage K-tile 0 into buffer 0 (3 loads/thread)
    async16(gAs, &Alds[0][tid * 8]);
    async16(gBs, &Blds[0][tid * 8]);
    async16(gBs + (size_t)128 * E_SZ, &Blds[0][4096 + tid * 8]);

#pragma unroll
    for (int t = 0; t < NT; ++t) {
        const int cur = t & 1;
        // BARRIER_A: everyone finished reading buf[1-cur] (iteration t-1)
        __builtin_amdgcn_s_barrier();
        __builtin_amdgcn_sched_barrier(0);
        if (t < NT - 1) {
            const int kOff = (t + 1) * BK;
            async16(gAs + kOff, &Alds[1 - cur][tid * 8]);
            async16(gBs + kOff, &Blds[1 - cur][tid * 8]);
            async16(gBs + (size_t)128 * E_SZ + kOff, &Blds[1 - cur][4096 + tid * 8]);
            // my 3 tile-t loads done; 3 prefetch loads stay in flight
            asm volatile("s_waitcnt vmcnt(3)" ::: "memory");
        } else {
            asm volatile("s_waitcnt vmcnt(0)" ::: "memory");
        }
        // BARRIER_B: all waves' tile-t loads have landed in buf[cur]
        __builtin_amdgcn_s_barrier();
        __builtin_amdgcn_sched_barrier(0);

        bf16x8 af[4], bfr[4];
#pragma unroll
        for (int mi = 0; mi < 4; ++mi)
            af[mi] = *(const bf16x8*)&Alds[cur][aBase + mi * 16 * BK];
#pragma unroll
        for (int ni = 0; ni < 4; ++ni)
            bfr[ni] = *(const bf16x8*)&Blds[cur][bBase + ni * 16 * BK];
#pragma unroll
        for (int mi = 0; mi < 4; ++mi)
#pragma unroll
            for (int ni = 0; ni < 4; ++ni)
                acc[mi][ni] = __builtin_amdgcn_mfma_f32_16x16x32_bf16(
                    af[mi], bfr[ni], acc[mi][ni], 0, 0, 0);
    }
    __builtin_amdgcn_sched_barrier(0);  // keep epilogue loads out of the K-loop

    // -------- epilogue: per-class (column) reductions --------
    int colG[4];
    float oS[4], iE[4];
#pragma unroll
    for (int ni = 0; ni < 4; ++ni) {
        colG[ni] = bn0 + wn * 64 + ni * 16 + l16;
        oS[ni] = oSimA[colG[ni]];
        iE[ni] = iEffA[colG[ni]];
    }
    float negE[4] = {0.f, 0.f, 0.f, 0.f};
    float negV[4] = {0.f, 0.f, 0.f, 0.f};
#pragma unroll
    for (int mi = 0; mi < 4; ++mi) {
#pragma unroll
        for (int r = 0; r < 4; ++r) {
            int rowL = wm * 64 + mi * 16 + quad * 4 + r;
            int tgt = tgtLds[rowL];
#pragma unroll
            for (int ni = 0; ni < 4; ++ni) {
                float cosv = acc[mi][ni][r];
                if (tgt == colG[ni]) {
                    // positive position (exactly one (bx,by) block per row)
                    atomicAdd(&posExp[colG[ni]],
                              __builtin_amdgcn_exp2f(A2LOG2E * (MRG - cosv)));
                    atomicAdd(&cCnt[colG[ni]], 1);
                } else {
                    float nv = (cosv < oS[ni]) ? iE[ni] : 1.0f;
                    negE[ni] += __builtin_amdgcn_exp2f(A2LOG2E * (cosv + MRG) * nv);
                    negV[ni] += nv;
                }
            }
        }
    }
    // quad-level register reduce: quad==0 lane holds the 64-row partial
#pragma unroll
    for (int ni = 0; ni < 4; ++ni) {
        negE[ni] += __shfl_xor(negE[ni], 16); negE[ni] += __shfl_xor(negE[ni], 32);
        negV[ni] += __shfl_xor(negV[ni], 16); negV[ni] += __shfl_xor(negV[ni], 32);
    }
    // combine the two wm-waves per column range in LDS, then one coalesced
    // global atomic per column.
    float* nEsh = scratch;          // 256 floats
    float* nVsh = scratch + BN;     // 256 floats
    scratch[tid & 511] = 0.0f;      // 512 threads zero 512 floats
    __syncthreads();
    if (quad == 0) {
#pragma unroll
        for (int ni = 0; ni < 4; ++ni) {
            int cl = wn * 64 + ni * 16 + l16;
            atomicAdd(&nEsh[cl], negE[ni]);
            atomicAdd(&nVsh[cl], negV[ni]);
        }
    }
    __syncthreads();
    if (tid < BN) {
        atomicAdd(&negExp[bn0 + tid], nEsh[tid]);
        atomicAdd(&negVals[bn0 + tid], nVsh[tid]);
    }
}

// ---------------- finalize: 16 blocks, last-block-ticket completes ----------------
__global__ __launch_bounds__(256) void finalize(
    const float* __restrict__ posExp, const float* __restrict__ negExp,
    const float* __restrict__ negVals, const int* __restrict__ cCnt,
    float* __restrict__ acc4, int* __restrict__ counter,
    float* __restrict__ out) {
    const int tid = threadIdx.x;
    float pt = 0.f, nt = 0.f, pws = 0.f, nws = 0.f;
#pragma unroll
    for (int j = 0; j < 4; ++j) {
        int c = blockIdx.x * 1024 + j * 256 + tid;
        pt += log1pf(posExp[c]);
        nt += log1pf(negExp[c]);
        int cnt = cCnt[c];
        pws += (cnt > 0) ? 1.0f : 0.0f;
        int Nc = B_SZ - cnt;
        nws += (Nc > 0) ? negVals[c] / (float)Nc : 0.0f;
    }
#pragma unroll
    for (int m = 1; m < 64; m <<= 1) {
        pt += __shfl_xor(pt, m);
        nt += __shfl_xor(nt, m);
        pws += __shfl_xor(pws, m);
        nws += __shfl_xor(nws, m);
    }
    __shared__ float red[4][4];
    int wv = tid >> 6;
    if ((tid & 63) == 0) {
        red[wv][0] = pt; red[wv][1] = nt; red[wv][2] = pws; red[wv][3] = nws;
    }
    __syncthreads();
    if (tid < 4) {
        float s = red[0][tid] + red[1][tid] + red[2][tid] + red[3][tid];
        atomicAdd(&acc4[tid], s);
    }
    __syncthreads();
    __threadfence();
    if (tid == 0) {
        int ticket = atomicAdd(counter, 1);
        if (ticket == 15) {
            float a0 = atomicAdd(&acc4[0], 0.0f);
            float a1 = atomicAdd(&acc4[1], 0.0f);
            float a2 = atomicAdd(&acc4[2], 0.0f);
            float a3 = atomicAdd(&acc4[3], 0.0f);
            out[0] = a0 / a2 + a1 / a3;
        }
    }
}

extern "C" void kernel_launch(void* const* d_in, const int* in_sizes, int n_in,
                              void* d_out, int out_size, void* d_ws, size_t ws_size,
                              hipStream_t stream) {
    const float* inputs = (const float*)d_in[0];
    const int* targets = (const int*)d_in[1];
    const float* proxies = (const float*)d_in[2];
    const float* effNum = (const float*)d_in[3];
    const float* lSim = (const float*)d_in[4];
    float* out = (float*)d_out;

    // workspace layout
    bf16* Pbf = (bf16*)d_ws;                        // C*E bf16  (16 MB)
    bf16* Abf = Pbf + (size_t)C_SZ * E_SZ;          // B*E bf16  (1 MB)
    float* oSim = (float*)(Abf + (size_t)B_SZ * E_SZ);
    float* iEff = oSim + C_SZ;
    float* posExp = iEff + C_SZ;                    // zeroBase starts here
    float* negExp = posExp + C_SZ;
    float* negVals = negExp + C_SZ;
    int* cCnt = (int*)(negVals + C_SZ);
    float* acc4 = (float*)(cCnt + C_SZ);
    int* counter = (int*)(acc4 + 4);

    prep_fused<<<4481, 256, 0, stream>>>(proxies, Pbf, inputs, Abf,
                                         effNum, lSim, oSim, iEff, posExp);
    gemm_epilogue<<<dim3(C_SZ / BN, B_SZ / BM), 512, 0, stream>>>(
        Abf, Pbf, targets, oSim, iEff, posExp, negExp, negVals, cCnt);
    finalize<<<16, 256, 0, stream>>>(posExp, negExp, negVals, cCnt,
                                     acc4, counter, out);
}